// Round 13
// baseline (180.942 us; speedup 1.0000x reference)
//
#include <hip/hip_runtime.h>
#include <hip/hip_fp16.h>
#include <math.h>

#define N_NODES 50000
#define NE      800000
#define NI4     (NE / 4)   // 200000 int4 edge-groups
#define INC     128
#define F1      128     // HEADS*HID
#define HEADS   8
#define HID     16
#define OUTC    16
#define NEG     0.2f
#define NBKT    196      // (N_NODES+255)>>8
#define NPART   128      // partition blocks
#define N1BLK   ((N_NODES + 63) / 64)   // 782 node1 blocks
#define CNTSZ   25088    // NBKT*NPART
#define CNTPAD  28672    // 1024*28 (scan reads int4-vectorized, pad zeroed)

union H4 { ushort4 u; __half h[4]; };
union H8 { uint4 u; __half h[8]; };

typedef _Float16 f16x8 __attribute__((ext_vector_type(8)));
typedef float    f32x4 __attribute__((ext_vector_type(4)));

// ==== fused: per-block dst histogram (blocks 0..127) + weight prep (128..199)
__global__ __launch_bounds__(256) void prep_kernel(const int* __restrict__ ei,
                                                   int* __restrict__ cnt,
                                                   const float* __restrict__ W1,
                                                   const float* __restrict__ as1,
                                                   const float* __restrict__ ad1,
                                                   __half* __restrict__ W1t,
                                                   __half* __restrict__ waT) {
    __shared__ int h[NBKT];
    int b = blockIdx.x, tid = threadIdx.x;
    if (b < NPART) {                     // edge histogram by dst>>8
        if (b == 0)                      // zero the scan pad region
            for (int i = CNTSZ + tid; i < CNTPAD; i += 256) cnt[i] = 0;
        for (int i = tid; i < NBKT; i += 256) h[i] = 0;
        __syncthreads();
        const int4* d4p = (const int4*)(ei + NE);
        for (int i4 = b * 256 + tid; i4 < NI4; i4 += NPART * 256) {
            int4 d4 = d4p[i4];
            atomicAdd(&h[d4.x >> 8], 1);
            atomicAdd(&h[d4.y >> 8], 1);
            atomicAdd(&h[d4.z >> 8], 1);
            atomicAdd(&h[d4.w >> 8], 1);
        }
        __syncthreads();
        for (int i = tid; i < NBKT; i += 256) cnt[i * NPART + b] = h[i];
    } else if (b < NPART + 64) {         // W1 transpose to fp16
        int i = (b - NPART) * 256 + tid;
        int k = i >> 7, nn = i & 127;
        W1t[nn * 128 + k] = __float2half(W1[k * 128 + nn]);
    } else {                             // folded attention matrix Wa
        int i = (b - NPART - 64) * 256 + tid;   // 0..2047
        int col = i & 15, k = i >> 4;
        int hh = col & 7;
        const float* av = (col < 8) ? as1 : ad1;
        float s = 0.f;
        #pragma unroll
        for (int cc = 0; cc < 16; ++cc)
            s += W1[k * 128 + hh * 16 + cc] * av[hh * 16 + cc];
        waT[col * 128 + k] = __float2half(s);   // B-frag layout [n=col][k]
    }
}

// ==== ILP scan: 28 values/thread held in registers (7 x int4), no guards ===
__global__ __launch_bounds__(1024) void scan25k(int* __restrict__ cnt) {
    __shared__ int part[1024];
    int tid = threadIdx.x;
    int base = tid * 28;
    int4 v[7];
    #pragma unroll
    for (int i = 0; i < 7; ++i) v[i] = ((const int4*)(cnt + base))[i];
    int s = 0;
    #pragma unroll
    for (int i = 0; i < 7; ++i) s += (v[i].x + v[i].y) + (v[i].z + v[i].w);
    part[tid] = s; __syncthreads();
    for (int off = 1; off < 1024; off <<= 1) {
        int t = (tid >= off) ? part[tid - off] : 0;
        __syncthreads();
        part[tid] += t;
        __syncthreads();
    }
    int run = part[tid] - s;
    #pragma unroll
    for (int i = 0; i < 7; ++i) {
        int4 w = v[i];
        int a0 = run; run += w.x;
        int a1 = run; run += w.y;
        int a2 = run; run += w.z;
        int a3 = run; run += w.w;
        ((int4*)(cnt + base))[i] = make_int4(a0, a1, a2, a3);
    }
}

// ==== standalone edge scatter (was fused with node1; node1 now hides sort) =
__global__ __launch_bounds__(256) void scatter_kernel(
    const int* __restrict__ ei, const int* __restrict__ cnt, int* __restrict__ tmp)
{
    __shared__ int cur[NBKT];
    int b = blockIdx.x, tid = threadIdx.x;
    for (int i = tid; i < NBKT; i += 256) cur[i] = cnt[i * NPART + b];
    __syncthreads();
    const int4* s4p = (const int4*)ei;
    const int4* d4p = (const int4*)(ei + NE);
    for (int i4 = b * 256 + tid; i4 < NI4; i4 += NPART * 256) {
        int4 s4 = s4p[i4];
        int4 d4 = d4p[i4];
        int p;
        p = atomicAdd(&cur[d4.x >> 8], 1); tmp[p] = s4.x | ((d4.x & 255) << 16);
        p = atomicAdd(&cur[d4.y >> 8], 1); tmp[p] = s4.y | ((d4.y & 255) << 16);
        p = atomicAdd(&cur[d4.z >> 8], 1); tmp[p] = s4.z | ((d4.z & 255) << 16);
        p = atomicAdd(&cur[d4.w >> 8], 1); tmp[p] = s4.w | ((d4.w & 255) << 16);
    }
}

// ==== fused: bucket sort (blocks 0..195) + Layer-1 MFMA GEMM (196..977) ====
// sort needs only scatter's tmp; node1 needs only prep's weights — the two
// are independent, so the ~10-15us sort hides under the node1 GEMM exactly
// as the scatter used to.
__global__ __launch_bounds__(256) void sort_node1_kernel(
    const int* __restrict__ tmp, const int* __restrict__ cnt,
    int* __restrict__ rowstart, int* __restrict__ csr,
    const float* __restrict__ x, const __half* __restrict__ W1t,
    const __half* __restrict__ waT,
    __half* __restrict__ hfeat, float* __restrict__ als, float* __restrict__ ald)
{
    __shared__ _Float16 Xh[64 * 136];    // 17.4 KB (sort aliases; node1 stages)
    __shared__ _Float16 Wt[128 * 136];   // 34.8 KB
    int b = blockIdx.x, tid = threadIdx.x;

    if (b < NBKT) {                      // ---- bucket sort branch ----
        int* h = (int*)Xh;               // 256 ints, aliased
        int base = cnt[b * NPART];
        int end  = (b == NBKT - 1) ? NE : cnt[(b + 1) * NPART];
        h[tid] = 0; __syncthreads();
        {
            int i = base + tid;
            for (; i + 768 < end; i += 1024) {
                int e0 = tmp[i], e1 = tmp[i + 256], e2 = tmp[i + 512], e3 = tmp[i + 768];
                atomicAdd(&h[(e0 >> 16) & 255], 1);
                atomicAdd(&h[(e1 >> 16) & 255], 1);
                atomicAdd(&h[(e2 >> 16) & 255], 1);
                atomicAdd(&h[(e3 >> 16) & 255], 1);
            }
            for (; i < end; i += 256)
                atomicAdd(&h[(tmp[i] >> 16) & 255], 1);
        }
        __syncthreads();
        int v = h[tid];
        for (int off = 1; off < 256; off <<= 1) {
            int t = (tid >= off) ? h[tid - off] : 0;
            __syncthreads();
            h[tid] += t;
            __syncthreads();
        }
        int excl = h[tid] - v;
        int n = (b << 8) + tid;
        if (n <= N_NODES) rowstart[n] = base + excl;
        __syncthreads();
        h[tid] = excl;
        __syncthreads();
        {
            int i = base + tid;
            for (; i + 768 < end; i += 1024) {
                int e0 = tmp[i], e1 = tmp[i + 256], e2 = tmp[i + 512], e3 = tmp[i + 768];
                int p0 = base + atomicAdd(&h[(e0 >> 16) & 255], 1); csr[p0] = e0 & 0xFFFF;
                int p1 = base + atomicAdd(&h[(e1 >> 16) & 255], 1); csr[p1] = e1 & 0xFFFF;
                int p2 = base + atomicAdd(&h[(e2 >> 16) & 255], 1); csr[p2] = e2 & 0xFFFF;
                int p3 = base + atomicAdd(&h[(e3 >> 16) & 255], 1); csr[p3] = e3 & 0xFFFF;
            }
            for (; i < end; i += 256) {
                int e = tmp[i];
                int p = base + atomicAdd(&h[(e >> 16) & 255], 1);
                csr[p] = e & 0xFFFF;
            }
        }
        return;
    }

    // ---- node1 branch ----
    int n0 = (b - NBKT) * 64;

    for (int idx = tid; idx < 128 * 16; idx += 256) {   // 16 x uint4 per row
        int row = idx >> 4, c8 = (idx & 15) * 8;
        *(uint4*)(&Wt[row * 136 + c8]) = ((const uint4*)W1t)[idx];
    }
    for (int idx = tid; idx < 64 * 32; idx += 256) {
        int m = idx >> 5, f4 = idx & 31;
        int n = n0 + m;
        float4 v = (n < N_NODES) ? ((const float4*)(x + (size_t)n * INC))[f4]
                                 : make_float4(0.f, 0.f, 0.f, 0.f);
        union { unsigned long long u; _Float16 h[4]; } p;
        p.h[0] = (_Float16)v.x; p.h[1] = (_Float16)v.y;
        p.h[2] = (_Float16)v.z; p.h[3] = (_Float16)v.w;
        *(unsigned long long*)(&Xh[m * 136 + f4 * 4]) = p.u;
    }
    __syncthreads();

    int wave = tid >> 6, lane = tid & 63;
    int colL = lane & 15, q = lane >> 4;
    int nb = wave * 32;

    f32x4 acc[4][2];
    #pragma unroll
    for (int mt = 0; mt < 4; ++mt)
        #pragma unroll
        for (int nt = 0; nt < 2; ++nt)
            acc[mt][nt] = (f32x4){0.f, 0.f, 0.f, 0.f};
    f32x4 acc2 = (f32x4){0.f, 0.f, 0.f, 0.f};   // logits, mt = wave

    #pragma unroll
    for (int kb = 0; kb < 4; ++kb) {
        int ko = kb * 32 + q * 8;
        f16x8 b0 = *(const f16x8*)(&Wt[(nb +  0 + colL) * 136 + ko]);
        f16x8 b1 = *(const f16x8*)(&Wt[(nb + 16 + colL) * 136 + ko]);
        #pragma unroll
        for (int mt = 0; mt < 4; ++mt) {
            f16x8 a = *(const f16x8*)(&Xh[(mt * 16 + colL) * 136 + ko]);
            acc[mt][0] = __builtin_amdgcn_mfma_f32_16x16x32_f16(a, b0, acc[mt][0], 0, 0, 0);
            acc[mt][1] = __builtin_amdgcn_mfma_f32_16x16x32_f16(a, b1, acc[mt][1], 0, 0, 0);
        }
        f16x8 bw = *(const f16x8*)(waT + colL * 128 + ko);           // global, L2-hot
        f16x8 aw = *(const f16x8*)(&Xh[(wave * 16 + colL) * 136 + ko]);
        acc2 = __builtin_amdgcn_mfma_f32_16x16x32_f16(aw, bw, acc2, 0, 0, 0);
    }

    // logit stores: split src/dst arrays (32B/node granularity for the gather)
    #pragma unroll
    for (int r = 0; r < 4; ++r) {
        int node = n0 + wave * 16 + q * 4 + r;
        if (node < N_NODES) {
            if (colL < 8) als[node * 8 + colL] = acc2[r];
            else          ald[node * 8 + (colL - 8)] = acc2[r];
        }
    }

    // ---- h stores: stage in LDS (Xh dead after kb loop), coalesced uint4.
    __syncthreads();                     // all Xh reads complete
    #pragma unroll
    for (int nt = 0; nt < 2; ++nt) {
        int col = nb + nt * 16 + colL;
        #pragma unroll
        for (int mt = 0; mt < 4; ++mt) {
            f32x4 d = acc[mt][nt];
            #pragma unroll
            for (int r = 0; r < 4; ++r) {
                int m = mt * 16 + q * 4 + r;
                Xh[m * 136 + col] = (_Float16)d[r];
            }
        }
    }
    __syncthreads();
    #pragma unroll
    for (int pass = 0; pass < 4; ++pass) {
        int idx = pass * 256 + tid;          // 0..1023: 64 rows x 16 uint4
        int m = idx >> 4, c8 = (idx & 15) * 8;
        int node = n0 + m;
        if (node < N_NODES)
            *(uint4*)(hfeat + (size_t)node * F1 + c8) = *(const uint4*)(&Xh[m * 136 + c8]);
    }
}

// ------ Layer 1 gather fused with Layer-2 node GEMM + logits ---------------
// 16 lanes/node, depth-2 pipeline; 2 nodes/unit sequentially. Pinned at
// ~47.5 us across 6 structural variants — do not reshape further.
__global__ __launch_bounds__(256) void agg1_node2_kernel(
    const int* __restrict__ rowstart, const int* __restrict__ csr,
    const __half* __restrict__ h1, const float* __restrict__ als,
    const float* __restrict__ ald, const float* __restrict__ b1,
    const float* __restrict__ W2, const float* __restrict__ a_s2,
    const float* __restrict__ a_d2,
    __half* __restrict__ h2, float* __restrict__ als2, float* __restrict__ ald2)
{
    __shared__ float    W2l[F1 * OUTC];      // 8 KB
    __shared__ _Float16 hbuf[32][136];       // 8.7 KB, padded rows

    int tid = threadIdx.x;
    for (int i = tid; i < F1 * OUTC; i += 256) W2l[i] = W2[i];

    int unit = tid >> 4;               // 0..15
    int lane = tid & 15;
    int c = lane * 8;
    int head = lane >> 1;

    for (int rep = 0; rep < 2; ++rep) {
        int nl = unit * 2 + rep;
        int n = blockIdx.x * 32 + nl;
        if (n < N_NODES) {
            float aldn = ald[n * 8 + head];
            float v0 = als[n * 8 + head] + aldn;
            v0 = fmaxf(v0, NEG * v0);
            float w0 = __expf(v0);
            float sum = w0;
            float a[8];
            {
                H8 hs; hs.u = *(const uint4*)(h1 + (size_t)n * F1 + c);
                #pragma unroll
                for (int i = 0; i < 8; ++i) a[i] = w0 * __half2float(hs.h[i]);
            }
            int r0 = rowstart[n], r1 = rowstart[n + 1];

            float vA = 0.f, vB = 0.f;
            H8 hA, hB; hA.u = make_uint4(0,0,0,0); hB.u = hA.u;
            int sC = 0, sD = 0;
            if (r0 < r1) {
                int s = csr[r0];
                float t = als[s * 8 + head] + aldn;
                vA = fmaxf(t, NEG * t);
                hA.u = *(const uint4*)(h1 + (size_t)s * F1 + c);
            }
            if (r0 + 1 < r1) {
                int s = csr[r0 + 1];
                float t = als[s * 8 + head] + aldn;
                vB = fmaxf(t, NEG * t);
                hB.u = *(const uint4*)(h1 + (size_t)s * F1 + c);
            }
            if (r0 + 2 < r1) sC = csr[r0 + 2];
            if (r0 + 3 < r1) sD = csr[r0 + 3];

            int k = r0;
            for (; k + 1 < r1; k += 2) {
                float vcA = vA, vcB = vB;
                H8 hcA = hA, hcB = hB;
                int sE = (k + 4 < r1) ? csr[k + 4] : 0;
                int sF = (k + 5 < r1) ? csr[k + 5] : 0;
                if (k + 2 < r1) {
                    float t = als[sC * 8 + head] + aldn;
                    vA = fmaxf(t, NEG * t);
                    hA.u = *(const uint4*)(h1 + (size_t)sC * F1 + c);
                }
                if (k + 3 < r1) {
                    float t = als[sD * 8 + head] + aldn;
                    vB = fmaxf(t, NEG * t);
                    hB.u = *(const uint4*)(h1 + (size_t)sD * F1 + c);
                }
                sC = sE; sD = sF;
                float wA = __expf(vcA), wB = __expf(vcB);
                sum += wA + wB;
                #pragma unroll
                for (int i = 0; i < 8; ++i) {
                    a[i] = fmaf(wA, __half2float(hcA.h[i]), a[i]);
                    a[i] = fmaf(wB, __half2float(hcB.h[i]), a[i]);
                }
            }
            if (k < r1) {                  // odd tail: consume slot A
                float wA = __expf(vA);
                sum += wA;
                #pragma unroll
                for (int i = 0; i < 8; ++i) a[i] = fmaf(wA, __half2float(hA.h[i]), a[i]);
            }

            float inv = 1.0f / sum;
            f16x8 hv;
            #pragma unroll
            for (int i = 0; i < 8; ++i) {
                float o = a[i] * inv + b1[c + i];
                o = o > 0.f ? o : (__expf(o) - 1.0f);
                hv[i] = (_Float16)o;
            }
            *(f16x8*)(&hbuf[nl][c]) = hv;
        }
        __builtin_amdgcn_sched_barrier(0);   // keep reps sequential (VGPR)
    }
    __syncthreads();

    // ---- layer-2 GEMM: 2 passes, thread (nl2, c2) -> one output element ---
    int c2 = tid & 15;
    #pragma unroll
    for (int pass = 0; pass < 2; ++pass) {
        int nl2 = (tid >> 4) + pass * 16;
        int n2 = blockIdx.x * 32 + nl2;
        float acc = 0.f;
        #pragma unroll
        for (int k8 = 0; k8 < 16; ++k8) {
            f16x8 xv = *(const f16x8*)(&hbuf[nl2][k8 * 8]);
            #pragma unroll
            for (int j = 0; j < 8; ++j)
                acc = fmaf((float)xv[j], W2l[(k8 * 8 + j) * OUTC + c2], acc);
        }
        float ps = acc * a_s2[c2];
        float pd = acc * a_d2[c2];
        #pragma unroll
        for (int m = 1; m < 16; m <<= 1) {
            ps += __shfl_xor(ps, m, 64);
            pd += __shfl_xor(pd, m, 64);
        }
        if (n2 < N_NODES) {
            h2[(size_t)n2 * OUTC + c2] = __float2half(acc);
            if (c2 == 0) { als2[n2] = ps; ald2[n2] = pd; }
        }
    }
}

// ------ Layer 2 gather: 4 lanes/node, 4 fp16/lane, depth-2, UNPAIRED ------
__global__ __launch_bounds__(256) void agg2_kernel(
    const int* __restrict__ rowstart, const int* __restrict__ csr,
    const __half* __restrict__ h2, const float* __restrict__ als,
    const float* __restrict__ ald, const float* __restrict__ b2,
    float* __restrict__ out)
{
    int tid = threadIdx.x;
    int n = blockIdx.x * 64 + (tid >> 2);
    if (n >= N_NODES) return;
    int c = (tid & 3) * 4;
    float aldn = ald[n];
    float v0 = als[n] + aldn;
    v0 = fmaxf(v0, NEG * v0);
    float w0 = __expf(v0);
    float sum = w0;
    H4 hs; hs.u = *(const ushort4*)(h2 + (size_t)n * OUTC + c);
    float a0 = w0 * __half2float(hs.h[0]), a1 = w0 * __half2float(hs.h[1]);
    float a2 = w0 * __half2float(hs.h[2]), a3 = w0 * __half2float(hs.h[3]);
    int r0 = rowstart[n], r1 = rowstart[n + 1];

    float vA = 0.f, vB = 0.f;
    H4 hA, hB; hA.u = make_ushort4(0,0,0,0); hB.u = hA.u;
    int sC = 0, sD = 0;
    if (r0 < r1) {
        int s = csr[r0];
        float t = als[s] + aldn;
        vA = fmaxf(t, NEG * t);
        hA.u = *(const ushort4*)(h2 + (size_t)s * OUTC + c);
    }
    if (r0 + 1 < r1) {
        int s = csr[r0 + 1];
        float t = als[s] + aldn;
        vB = fmaxf(t, NEG * t);
        hB.u = *(const ushort4*)(h2 + (size_t)s * OUTC + c);
    }
    if (r0 + 2 < r1) sC = csr[r0 + 2];
    if (r0 + 3 < r1) sD = csr[r0 + 3];

    int k = r0;
    for (; k + 1 < r1; k += 2) {
        float vcA = vA, vcB = vB;
        H4 hcA = hA, hcB = hB;
        int sE = (k + 4 < r1) ? csr[k + 4] : 0;
        int sF = (k + 5 < r1) ? csr[k + 5] : 0;
        if (k + 2 < r1) {
            float t = als[sC] + aldn;
            vA = fmaxf(t, NEG * t);
            hA.u = *(const ushort4*)(h2 + (size_t)sC * OUTC + c);
        }
        if (k + 3 < r1) {
            float t = als[sD] + aldn;
            vB = fmaxf(t, NEG * t);
            hB.u = *(const ushort4*)(h2 + (size_t)sD * OUTC + c);
        }
        sC = sE; sD = sF;
        float wA = __expf(vcA), wB = __expf(vcB);
        sum += wA + wB;
        a0 = fmaf(wA, __half2float(hcA.h[0]), a0); a0 = fmaf(wB, __half2float(hcB.h[0]), a0);
        a1 = fmaf(wA, __half2float(hcA.h[1]), a1); a1 = fmaf(wB, __half2float(hcB.h[1]), a1);
        a2 = fmaf(wA, __half2float(hcA.h[2]), a2); a2 = fmaf(wB, __half2float(hcB.h[2]), a2);
        a3 = fmaf(wA, __half2float(hcA.h[3]), a3); a3 = fmaf(wB, __half2float(hcB.h[3]), a3);
    }
    if (k < r1) {
        float wA = __expf(vA);
        sum += wA;
        a0 = fmaf(wA, __half2float(hA.h[0]), a0);
        a1 = fmaf(wA, __half2float(hA.h[1]), a1);
        a2 = fmaf(wA, __half2float(hA.h[2]), a2);
        a3 = fmaf(wA, __half2float(hA.h[3]), a3);
    }

    float inv = 1.0f / sum;
    float4 bv = *(const float4*)(b2 + c);
    float4 o;
    o.x = a0 * inv + bv.x; o.y = a1 * inv + bv.y;
    o.z = a2 * inv + bv.z; o.w = a3 * inv + bv.w;
    *(float4*)(out + (size_t)n * OUTC + c) = o;
}

extern "C" void kernel_launch(void* const* d_in, const int* in_sizes, int n_in,
                              void* d_out, int out_size, void* d_ws, size_t ws_size,
                              hipStream_t stream)
{
    const float* x   = (const float*)d_in[0];
    const int*   ei  = (const int*)  d_in[1];
    const float* W1  = (const float*)d_in[2];
    const float* as1 = (const float*)d_in[3];
    const float* ad1 = (const float*)d_in[4];
    const float* b1  = (const float*)d_in[5];
    const float* W2  = (const float*)d_in[6];
    const float* as2 = (const float*)d_in[7];
    const float* ad2 = (const float*)d_in[8];
    const float* b2  = (const float*)d_in[9];
    float* out = (float*)d_out;

    char* wsb = (char*)d_ws;
    const size_t SZ_H1 = (size_t)N_NODES * F1 * sizeof(__half);   // 12.8 MB
    __half* h1h  = (__half*)wsb;                                  // node-major [N][128]
    float*  als1 = (float*)(wsb + SZ_H1);                         // [N][8] f32
    float*  ald1 = als1 + (size_t)N_NODES * 8;                    // [N][8] f32
    __half* h2f  = (__half*)(ald1 + (size_t)N_NODES * 8);         // N*16 fp16
    float*  als2 = (float*)(h2f + (size_t)N_NODES * OUTC);        // N
    float*  ald2 = als2 + N_NODES;                                // N
    __half* w1t  = (__half*)(ald2 + N_NODES);                     // 128*128 fp16
    __half* waT  = w1t + INC * F1;                                // 16*128 fp16
    int*    tmp  = (int*)(waT + 16 * INC);                        // NE ints (packed)
    int*    cnt  = tmp + NE;                                      // CNTPAD (16B aligned)
    int*    csr  = cnt + CNTPAD;                                  // NE
    int*    rowstart = csr + NE;                                  // N+1

    // ---- CSR build + weight prep ----
    prep_kernel   <<<NPART + 72, 256, 0, stream>>>(ei, cnt, W1, as1, ad1, w1t, waT);
    scan25k       <<<1, 1024, 0, stream>>>(cnt);
    scatter_kernel<<<NPART, 256, 0, stream>>>(ei, cnt, tmp);

    // ---- bucket sort hidden under Layer-1 GEMM ----
    sort_node1_kernel<<<NBKT + N1BLK, 256, 0, stream>>>(tmp, cnt, rowstart, csr,
                                                        x, w1t, waT, h1h, als1, ald1);

    // ---- layer 1 gather + layer 2 node GEMM (fused, 2 nodes/unit) ----
    agg1_node2_kernel<<<(N_NODES + 31) / 32, 256, 0, stream>>>(rowstart, csr, h1h, als1, ald1, b1,
                                                               W2, as2, ad2, h2f, als2, ald2);

    // ---- layer 2 gather (unpaired, 782 blocks) ----
    agg2_kernel<<<(N_NODES + 63) / 64, 256, 0, stream>>>(rowstart, csr, h2f, als2, ald2, b2, out);
}

// Round 14
// 176.428 us; speedup vs baseline: 1.0256x; 1.0256x over previous
//
#include <hip/hip_runtime.h>
#include <hip/hip_fp16.h>
#include <math.h>

#define N_NODES 50000
#define NE      800000
#define NI4     (NE / 4)   // 200000 int4 edge-groups
#define INC     128
#define F1      128     // HEADS*HID
#define HEADS   8
#define HID     16
#define OUTC    16
#define NEG     0.2f
#define NBKT    196      // (N_NODES+255)>>8
#define NPART   128      // partition blocks
#define N1BLK   ((N_NODES + 63) / 64)   // 782 node1 blocks
#define CNTSZ   25088    // NBKT*NPART
#define CNTPAD  28672    // 1024*28 (scan reads int4-vectorized, pad zeroed)

union H4 { ushort4 u; __half h[4]; };
union H8 { uint4 u; __half h[8]; };

typedef _Float16 f16x8 __attribute__((ext_vector_type(8)));
typedef float    f32x4 __attribute__((ext_vector_type(4)));

// ==== fused: per-block dst histogram (blocks 0..127) + weight prep (128..199)
// Hist loop int4-vectorized: 4 independent dst loads per iteration cut the
// serial load->atomic chain 4x (R5 scan lesson generalized).
__global__ __launch_bounds__(256) void prep_kernel(const int* __restrict__ ei,
                                                   int* __restrict__ cnt,
                                                   const float* __restrict__ W1,
                                                   const float* __restrict__ as1,
                                                   const float* __restrict__ ad1,
                                                   __half* __restrict__ W1t,
                                                   __half* __restrict__ waT) {
    __shared__ int h[NBKT];
    int b = blockIdx.x, tid = threadIdx.x;
    if (b < NPART) {                     // edge histogram by dst>>8
        if (b == 0)                      // zero the scan pad region
            for (int i = CNTSZ + tid; i < CNTPAD; i += 256) cnt[i] = 0;
        for (int i = tid; i < NBKT; i += 256) h[i] = 0;
        __syncthreads();
        const int4* d4p = (const int4*)(ei + NE);
        for (int i4 = b * 256 + tid; i4 < NI4; i4 += NPART * 256) {
            int4 d4 = d4p[i4];
            atomicAdd(&h[d4.x >> 8], 1);
            atomicAdd(&h[d4.y >> 8], 1);
            atomicAdd(&h[d4.z >> 8], 1);
            atomicAdd(&h[d4.w >> 8], 1);
        }
        __syncthreads();
        for (int i = tid; i < NBKT; i += 256) cnt[i * NPART + b] = h[i];
    } else if (b < NPART + 64) {         // W1 transpose to fp16
        int i = (b - NPART) * 256 + tid;
        int k = i >> 7, nn = i & 127;
        W1t[nn * 128 + k] = __float2half(W1[k * 128 + nn]);
    } else {                             // folded attention matrix Wa
        int i = (b - NPART - 64) * 256 + tid;   // 0..2047
        int col = i & 15, k = i >> 4;
        int hh = col & 7;
        const float* av = (col < 8) ? as1 : ad1;
        float s = 0.f;
        #pragma unroll
        for (int cc = 0; cc < 16; ++cc)
            s += W1[k * 128 + hh * 16 + cc] * av[hh * 16 + cc];
        waT[col * 128 + k] = __float2half(s);   // B-frag layout [n=col][k]
    }
}

// ==== ILP scan: 28 values/thread held in registers (7 x int4), no guards ===
__global__ __launch_bounds__(1024) void scan25k(int* __restrict__ cnt) {
    __shared__ int part[1024];
    int tid = threadIdx.x;
    int base = tid * 28;
    int4 v[7];
    #pragma unroll
    for (int i = 0; i < 7; ++i) v[i] = ((const int4*)(cnt + base))[i];
    int s = 0;
    #pragma unroll
    for (int i = 0; i < 7; ++i) s += (v[i].x + v[i].y) + (v[i].z + v[i].w);
    part[tid] = s; __syncthreads();
    for (int off = 1; off < 1024; off <<= 1) {
        int t = (tid >= off) ? part[tid - off] : 0;
        __syncthreads();
        part[tid] += t;
        __syncthreads();
    }
    int run = part[tid] - s;
    #pragma unroll
    for (int i = 0; i < 7; ++i) {
        int4 w = v[i];
        int a0 = run; run += w.x;
        int a1 = run; run += w.y;
        int a2 = run; run += w.z;
        int a3 = run; run += w.w;
        ((int4*)(cnt + base))[i] = make_int4(a0, a1, a2, a3);
    }
}

// ==== fused: edge scatter (blocks 0..127) + Layer-1 MFMA GEMM (128..909) ====
// Scatter branch int4-vectorized with the SAME i4->block mapping as prep's
// histogram (counts must match per (bucket, block)).
__global__ __launch_bounds__(256) void scatter_node1_kernel(
    const int* __restrict__ ei, const int* __restrict__ cnt, int* __restrict__ tmp,
    const float* __restrict__ x, const __half* __restrict__ W1t,
    const __half* __restrict__ waT,
    __half* __restrict__ hfeat, float* __restrict__ als, float* __restrict__ ald)
{
    __shared__ _Float16 Xh[64 * 136];    // 17.4 KB (input stage, then output stage)
    __shared__ _Float16 Wt[128 * 136];   // 34.8 KB (pad 8 halves/row)
    int b = blockIdx.x, tid = threadIdx.x;

    if (b < NPART) {                     // ---- edge scatter branch ----
        int* cur = (int*)Xh;             // alias LDS (only need NBKT ints)
        for (int i = tid; i < NBKT; i += 256) cur[i] = cnt[i * NPART + b];
        __syncthreads();
        const int4* s4p = (const int4*)ei;
        const int4* d4p = (const int4*)(ei + NE);
        for (int i4 = b * 256 + tid; i4 < NI4; i4 += NPART * 256) {
            int4 s4 = s4p[i4];
            int4 d4 = d4p[i4];
            int p;
            p = atomicAdd(&cur[d4.x >> 8], 1); tmp[p] = s4.x | ((d4.x & 255) << 16);
            p = atomicAdd(&cur[d4.y >> 8], 1); tmp[p] = s4.y | ((d4.y & 255) << 16);
            p = atomicAdd(&cur[d4.z >> 8], 1); tmp[p] = s4.z | ((d4.z & 255) << 16);
            p = atomicAdd(&cur[d4.w >> 8], 1); tmp[p] = s4.w | ((d4.w & 255) << 16);
        }
        return;
    }

    // ---- node1 branch ----
    int n0 = (b - NPART) * 64;

    for (int idx = tid; idx < 128 * 16; idx += 256) {   // 16 x uint4 per row
        int row = idx >> 4, c8 = (idx & 15) * 8;
        *(uint4*)(&Wt[row * 136 + c8]) = ((const uint4*)W1t)[idx];
    }
    for (int idx = tid; idx < 64 * 32; idx += 256) {
        int m = idx >> 5, f4 = idx & 31;
        int n = n0 + m;
        float4 v = (n < N_NODES) ? ((const float4*)(x + (size_t)n * INC))[f4]
                                 : make_float4(0.f, 0.f, 0.f, 0.f);
        union { unsigned long long u; _Float16 h[4]; } p;
        p.h[0] = (_Float16)v.x; p.h[1] = (_Float16)v.y;
        p.h[2] = (_Float16)v.z; p.h[3] = (_Float16)v.w;
        *(unsigned long long*)(&Xh[m * 136 + f4 * 4]) = p.u;
    }
    __syncthreads();

    int wave = tid >> 6, lane = tid & 63;
    int colL = lane & 15, q = lane >> 4;
    int nb = wave * 32;

    f32x4 acc[4][2];
    #pragma unroll
    for (int mt = 0; mt < 4; ++mt)
        #pragma unroll
        for (int nt = 0; nt < 2; ++nt)
            acc[mt][nt] = (f32x4){0.f, 0.f, 0.f, 0.f};
    f32x4 acc2 = (f32x4){0.f, 0.f, 0.f, 0.f};   // logits, mt = wave

    #pragma unroll
    for (int kb = 0; kb < 4; ++kb) {
        int ko = kb * 32 + q * 8;
        f16x8 b0 = *(const f16x8*)(&Wt[(nb +  0 + colL) * 136 + ko]);
        f16x8 b1 = *(const f16x8*)(&Wt[(nb + 16 + colL) * 136 + ko]);
        #pragma unroll
        for (int mt = 0; mt < 4; ++mt) {
            f16x8 a = *(const f16x8*)(&Xh[(mt * 16 + colL) * 136 + ko]);
            acc[mt][0] = __builtin_amdgcn_mfma_f32_16x16x32_f16(a, b0, acc[mt][0], 0, 0, 0);
            acc[mt][1] = __builtin_amdgcn_mfma_f32_16x16x32_f16(a, b1, acc[mt][1], 0, 0, 0);
        }
        f16x8 bw = *(const f16x8*)(waT + colL * 128 + ko);           // global, L2-hot
        f16x8 aw = *(const f16x8*)(&Xh[(wave * 16 + colL) * 136 + ko]);
        acc2 = __builtin_amdgcn_mfma_f32_16x16x32_f16(aw, bw, acc2, 0, 0, 0);
    }

    // logit stores: split src/dst arrays (32B/node granularity for the gather)
    #pragma unroll
    for (int r = 0; r < 4; ++r) {
        int node = n0 + wave * 16 + q * 4 + r;
        if (node < N_NODES) {
            if (colL < 8) als[node * 8 + colL] = acc2[r];
            else          ald[node * 8 + (colL - 8)] = acc2[r];
        }
    }

    // ---- h stores: stage in LDS (Xh dead after kb loop), coalesced uint4.
    __syncthreads();                     // all Xh reads complete
    #pragma unroll
    for (int nt = 0; nt < 2; ++nt) {
        int col = nb + nt * 16 + colL;
        #pragma unroll
        for (int mt = 0; mt < 4; ++mt) {
            f32x4 d = acc[mt][nt];
            #pragma unroll
            for (int r = 0; r < 4; ++r) {
                int m = mt * 16 + q * 4 + r;
                Xh[m * 136 + col] = (_Float16)d[r];
            }
        }
    }
    __syncthreads();
    #pragma unroll
    for (int pass = 0; pass < 4; ++pass) {
        int idx = pass * 256 + tid;          // 0..1023: 64 rows x 16 uint4
        int m = idx >> 4, c8 = (idx & 15) * 8;
        int node = n0 + m;
        if (node < N_NODES)
            *(uint4*)(hfeat + (size_t)node * F1 + c8) = *(const uint4*)(&Xh[m * 136 + c8]);
    }
}

// ==== bucket sort: both passes batch 4 independent tmp loads per iteration
__global__ __launch_bounds__(256) void bucket_sort(const int* __restrict__ tmp,
                                                   const int* __restrict__ cnt,
                                                   int* __restrict__ rowstart,
                                                   int* __restrict__ csr) {
    __shared__ int h[256];
    int b = blockIdx.x, tid = threadIdx.x;
    int base = cnt[b * NPART];
    int end  = (b == NBKT - 1) ? NE : cnt[(b + 1) * NPART];
    h[tid] = 0; __syncthreads();
    {
        int i = base + tid;
        for (; i + 768 < end; i += 1024) {
            int e0 = tmp[i], e1 = tmp[i + 256], e2 = tmp[i + 512], e3 = tmp[i + 768];
            atomicAdd(&h[(e0 >> 16) & 255], 1);
            atomicAdd(&h[(e1 >> 16) & 255], 1);
            atomicAdd(&h[(e2 >> 16) & 255], 1);
            atomicAdd(&h[(e3 >> 16) & 255], 1);
        }
        for (; i < end; i += 256)
            atomicAdd(&h[(tmp[i] >> 16) & 255], 1);
    }
    __syncthreads();
    int v = h[tid];
    for (int off = 1; off < 256; off <<= 1) {
        int t = (tid >= off) ? h[tid - off] : 0;
        __syncthreads();
        h[tid] += t;
        __syncthreads();
    }
    int excl = h[tid] - v;
    int n = (b << 8) + tid;
    if (n <= N_NODES) rowstart[n] = base + excl;
    __syncthreads();
    h[tid] = excl;
    __syncthreads();
    {
        int i = base + tid;
        for (; i + 768 < end; i += 1024) {
            int e0 = tmp[i], e1 = tmp[i + 256], e2 = tmp[i + 512], e3 = tmp[i + 768];
            int p0 = base + atomicAdd(&h[(e0 >> 16) & 255], 1); csr[p0] = e0 & 0xFFFF;
            int p1 = base + atomicAdd(&h[(e1 >> 16) & 255], 1); csr[p1] = e1 & 0xFFFF;
            int p2 = base + atomicAdd(&h[(e2 >> 16) & 255], 1); csr[p2] = e2 & 0xFFFF;
            int p3 = base + atomicAdd(&h[(e3 >> 16) & 255], 1); csr[p3] = e3 & 0xFFFF;
        }
        for (; i < end; i += 256) {
            int e = tmp[i];
            int p = base + atomicAdd(&h[(e >> 16) & 255], 1);
            csr[p] = e & 0xFFFF;
        }
    }
}

// ------ Layer 1 gather fused with Layer-2 node GEMM + logits ---------------
// 16 lanes/node, depth-2 pipeline; 2 nodes/unit sequentially. Pinned at
// ~47.5 us across 6 structural variants — do not reshape further.
__global__ __launch_bounds__(256) void agg1_node2_kernel(
    const int* __restrict__ rowstart, const int* __restrict__ csr,
    const __half* __restrict__ h1, const float* __restrict__ als,
    const float* __restrict__ ald, const float* __restrict__ b1,
    const float* __restrict__ W2, const float* __restrict__ a_s2,
    const float* __restrict__ a_d2,
    __half* __restrict__ h2, float* __restrict__ als2, float* __restrict__ ald2)
{
    __shared__ float    W2l[F1 * OUTC];      // 8 KB
    __shared__ _Float16 hbuf[32][136];       // 8.7 KB, padded rows

    int tid = threadIdx.x;
    for (int i = tid; i < F1 * OUTC; i += 256) W2l[i] = W2[i];

    int unit = tid >> 4;               // 0..15
    int lane = tid & 15;
    int c = lane * 8;
    int head = lane >> 1;

    for (int rep = 0; rep < 2; ++rep) {
        int nl = unit * 2 + rep;
        int n = blockIdx.x * 32 + nl;
        if (n < N_NODES) {
            float aldn = ald[n * 8 + head];
            float v0 = als[n * 8 + head] + aldn;
            v0 = fmaxf(v0, NEG * v0);
            float w0 = __expf(v0);
            float sum = w0;
            float a[8];
            {
                H8 hs; hs.u = *(const uint4*)(h1 + (size_t)n * F1 + c);
                #pragma unroll
                for (int i = 0; i < 8; ++i) a[i] = w0 * __half2float(hs.h[i]);
            }
            int r0 = rowstart[n], r1 = rowstart[n + 1];

            float vA = 0.f, vB = 0.f;
            H8 hA, hB; hA.u = make_uint4(0,0,0,0); hB.u = hA.u;
            int sC = 0, sD = 0;
            if (r0 < r1) {
                int s = csr[r0];
                float t = als[s * 8 + head] + aldn;
                vA = fmaxf(t, NEG * t);
                hA.u = *(const uint4*)(h1 + (size_t)s * F1 + c);
            }
            if (r0 + 1 < r1) {
                int s = csr[r0 + 1];
                float t = als[s * 8 + head] + aldn;
                vB = fmaxf(t, NEG * t);
                hB.u = *(const uint4*)(h1 + (size_t)s * F1 + c);
            }
            if (r0 + 2 < r1) sC = csr[r0 + 2];
            if (r0 + 3 < r1) sD = csr[r0 + 3];

            int k = r0;
            for (; k + 1 < r1; k += 2) {
                float vcA = vA, vcB = vB;
                H8 hcA = hA, hcB = hB;
                int sE = (k + 4 < r1) ? csr[k + 4] : 0;
                int sF = (k + 5 < r1) ? csr[k + 5] : 0;
                if (k + 2 < r1) {
                    float t = als[sC * 8 + head] + aldn;
                    vA = fmaxf(t, NEG * t);
                    hA.u = *(const uint4*)(h1 + (size_t)sC * F1 + c);
                }
                if (k + 3 < r1) {
                    float t = als[sD * 8 + head] + aldn;
                    vB = fmaxf(t, NEG * t);
                    hB.u = *(const uint4*)(h1 + (size_t)sD * F1 + c);
                }
                sC = sE; sD = sF;
                float wA = __expf(vcA), wB = __expf(vcB);
                sum += wA + wB;
                #pragma unroll
                for (int i = 0; i < 8; ++i) {
                    a[i] = fmaf(wA, __half2float(hcA.h[i]), a[i]);
                    a[i] = fmaf(wB, __half2float(hcB.h[i]), a[i]);
                }
            }
            if (k < r1) {                  // odd tail: consume slot A
                float wA = __expf(vA);
                sum += wA;
                #pragma unroll
                for (int i = 0; i < 8; ++i) a[i] = fmaf(wA, __half2float(hA.h[i]), a[i]);
            }

            float inv = 1.0f / sum;
            f16x8 hv;
            #pragma unroll
            for (int i = 0; i < 8; ++i) {
                float o = a[i] * inv + b1[c + i];
                o = o > 0.f ? o : (__expf(o) - 1.0f);
                hv[i] = (_Float16)o;
            }
            *(f16x8*)(&hbuf[nl][c]) = hv;
        }
        __builtin_amdgcn_sched_barrier(0);   // keep reps sequential (VGPR)
    }
    __syncthreads();

    // ---- layer-2 GEMM: 2 passes, thread (nl2, c2) -> one output element ---
    int c2 = tid & 15;
    #pragma unroll
    for (int pass = 0; pass < 2; ++pass) {
        int nl2 = (tid >> 4) + pass * 16;
        int n2 = blockIdx.x * 32 + nl2;
        float acc = 0.f;
        #pragma unroll
        for (int k8 = 0; k8 < 16; ++k8) {
            f16x8 xv = *(const f16x8*)(&hbuf[nl2][k8 * 8]);
            #pragma unroll
            for (int j = 0; j < 8; ++j)
                acc = fmaf((float)xv[j], W2l[(k8 * 8 + j) * OUTC + c2], acc);
        }
        float ps = acc * a_s2[c2];
        float pd = acc * a_d2[c2];
        #pragma unroll
        for (int m = 1; m < 16; m <<= 1) {
            ps += __shfl_xor(ps, m, 64);
            pd += __shfl_xor(pd, m, 64);
        }
        if (n2 < N_NODES) {
            h2[(size_t)n2 * OUTC + c2] = __float2half(acc);
            if (c2 == 0) { als2[n2] = ps; ald2[n2] = pd; }
        }
    }
}

// ------ Layer 2 gather: 4 lanes/node, 4 fp16/lane, depth-2, UNPAIRED ------
__global__ __launch_bounds__(256) void agg2_kernel(
    const int* __restrict__ rowstart, const int* __restrict__ csr,
    const __half* __restrict__ h2, const float* __restrict__ als,
    const float* __restrict__ ald, const float* __restrict__ b2,
    float* __restrict__ out)
{
    int tid = threadIdx.x;
    int n = blockIdx.x * 64 + (tid >> 2);
    if (n >= N_NODES) return;
    int c = (tid & 3) * 4;
    float aldn = ald[n];
    float v0 = als[n] + aldn;
    v0 = fmaxf(v0, NEG * v0);
    float w0 = __expf(v0);
    float sum = w0;
    H4 hs; hs.u = *(const ushort4*)(h2 + (size_t)n * OUTC + c);
    float a0 = w0 * __half2float(hs.h[0]), a1 = w0 * __half2float(hs.h[1]);
    float a2 = w0 * __half2float(hs.h[2]), a3 = w0 * __half2float(hs.h[3]);
    int r0 = rowstart[n], r1 = rowstart[n + 1];

    float vA = 0.f, vB = 0.f;
    H4 hA, hB; hA.u = make_ushort4(0,0,0,0); hB.u = hA.u;
    int sC = 0, sD = 0;
    if (r0 < r1) {
        int s = csr[r0];
        float t = als[s] + aldn;
        vA = fmaxf(t, NEG * t);
        hA.u = *(const ushort4*)(h2 + (size_t)s * OUTC + c);
    }
    if (r0 + 1 < r1) {
        int s = csr[r0 + 1];
        float t = als[s] + aldn;
        vB = fmaxf(t, NEG * t);
        hB.u = *(const ushort4*)(h2 + (size_t)s * OUTC + c);
    }
    if (r0 + 2 < r1) sC = csr[r0 + 2];
    if (r0 + 3 < r1) sD = csr[r0 + 3];

    int k = r0;
    for (; k + 1 < r1; k += 2) {
        float vcA = vA, vcB = vB;
        H4 hcA = hA, hcB = hB;
        int sE = (k + 4 < r1) ? csr[k + 4] : 0;
        int sF = (k + 5 < r1) ? csr[k + 5] : 0;
        if (k + 2 < r1) {
            float t = als[sC] + aldn;
            vA = fmaxf(t, NEG * t);
            hA.u = *(const ushort4*)(h2 + (size_t)sC * OUTC + c);
        }
        if (k + 3 < r1) {
            float t = als[sD] + aldn;
            vB = fmaxf(t, NEG * t);
            hB.u = *(const ushort4*)(h2 + (size_t)sD * OUTC + c);
        }
        sC = sE; sD = sF;
        float wA = __expf(vcA), wB = __expf(vcB);
        sum += wA + wB;
        a0 = fmaf(wA, __half2float(hcA.h[0]), a0); a0 = fmaf(wB, __half2float(hcB.h[0]), a0);
        a1 = fmaf(wA, __half2float(hcA.h[1]), a1); a1 = fmaf(wB, __half2float(hcB.h[1]), a1);
        a2 = fmaf(wA, __half2float(hcA.h[2]), a2); a2 = fmaf(wB, __half2float(hcB.h[2]), a2);
        a3 = fmaf(wA, __half2float(hcA.h[3]), a3); a3 = fmaf(wB, __half2float(hcB.h[3]), a3);
    }
    if (k < r1) {
        float wA = __expf(vA);
        sum += wA;
        a0 = fmaf(wA, __half2float(hA.h[0]), a0);
        a1 = fmaf(wA, __half2float(hA.h[1]), a1);
        a2 = fmaf(wA, __half2float(hA.h[2]), a2);
        a3 = fmaf(wA, __half2float(hA.h[3]), a3);
    }

    float inv = 1.0f / sum;
    float4 bv = *(const float4*)(b2 + c);
    float4 o;
    o.x = a0 * inv + bv.x; o.y = a1 * inv + bv.y;
    o.z = a2 * inv + bv.z; o.w = a3 * inv + bv.w;
    *(float4*)(out + (size_t)n * OUTC + c) = o;
}

extern "C" void kernel_launch(void* const* d_in, const int* in_sizes, int n_in,
                              void* d_out, int out_size, void* d_ws, size_t ws_size,
                              hipStream_t stream)
{
    const float* x   = (const float*)d_in[0];
    const int*   ei  = (const int*)  d_in[1];
    const float* W1  = (const float*)d_in[2];
    const float* as1 = (const float*)d_in[3];
    const float* ad1 = (const float*)d_in[4];
    const float* b1  = (const float*)d_in[5];
    const float* W2  = (const float*)d_in[6];
    const float* as2 = (const float*)d_in[7];
    const float* ad2 = (const float*)d_in[8];
    const float* b2  = (const float*)d_in[9];
    float* out = (float*)d_out;

    char* wsb = (char*)d_ws;
    const size_t SZ_H1 = (size_t)N_NODES * F1 * sizeof(__half);   // 12.8 MB
    __half* h1h  = (__half*)wsb;                                  // node-major [N][128]
    float*  als1 = (float*)(wsb + SZ_H1);                         // [N][8] f32
    float*  ald1 = als1 + (size_t)N_NODES * 8;                    // [N][8] f32
    __half* h2f  = (__half*)(ald1 + (size_t)N_NODES * 8);         // N*16 fp16
    float*  als2 = (float*)(h2f + (size_t)N_NODES * OUTC);        // N
    float*  ald2 = als2 + N_NODES;                                // N
    __half* w1t  = (__half*)(ald2 + N_NODES);                     // 128*128 fp16
    __half* waT  = w1t + INC * F1;                                // 16*128 fp16
    int*    tmp  = (int*)(waT + 16 * INC);                        // NE ints (packed)
    int*    cnt  = tmp + NE;                                      // CNTPAD (16B aligned)
    int*    csr  = cnt + CNTPAD;                                  // NE
    int*    rowstart = csr + NE;                                  // N+1

    // ---- CSR build + weight prep; scatter hidden under node1 ----
    prep_kernel <<<NPART + 72, 256, 0, stream>>>(ei, cnt, W1, as1, ad1, w1t, waT);
    scan25k     <<<1, 1024, 0, stream>>>(cnt);
    scatter_node1_kernel<<<NPART + N1BLK, 256, 0, stream>>>(ei, cnt, tmp,
                                                            x, w1t, waT, h1h, als1, ald1);
    bucket_sort <<<NBKT, 256, 0, stream>>>(tmp, cnt, rowstart, csr);

    // ---- layer 1 gather + layer 2 node GEMM (fused, 2 nodes/unit) ----
    agg1_node2_kernel<<<(N_NODES + 31) / 32, 256, 0, stream>>>(rowstart, csr, h1h, als1, ald1, b1,
                                                               W2, as2, ad2, h2f, als2, ald2);

    // ---- layer 2 gather (unpaired, 782 blocks) ----
    agg2_kernel<<<(N_NODES + 63) / 64, 256, 0, stream>>>(rowstart, csr, h2f, als2, ald2, b2, out);
}